// Round 5
// baseline (153.761 us; speedup 1.0000x reference)
//
#include <hip/hip_runtime.h>
#include <hip/hip_fp16.h>

// WeightedMSELoss: mean over [B,2] of |pred-label| * (1 + a - a*w[cell(pred)])
// R3: latency-bound (50 us, ~0 HBM warm, VALU 19%, occupancy 37%).
// R4 levers:
//  - fp16 weight table in LDS: 80.8 KB/block -> 2 blocks/CU -> 32 waves/CU.
//  - index math: floor((p*180-90)/0.9)+100 == floor(p*200); kills all 4 fp32
//    divisions per iteration (boundary-ulp cell flips perturb mean by ~2e-9).

constexpr int   GRIDN  = 201;
constexpr int   GRIDSZ = GRIDN * GRIDN;   // 40401
constexpr float ALPHA  = 0.1f;

__global__ __launch_bounds__(1024, 8) void wmse_reduce(
    const float4* __restrict__ pred4,
    const float4* __restrict__ lab4,
    const float*  __restrict__ wg,
    float*        __restrict__ out,
    int n4, float scale)
{
    __shared__ __half wg_lds[GRIDSZ];         // 80,802 B -> 2 blocks/CU

    // Stage + compress weight grid: vectorized f32x4 -> f16x4.
    const float4* wg4 = (const float4*)wg;
    for (int j = threadIdx.x; j < GRIDSZ / 4; j += 1024) {
        const float4 v = wg4[j];
        __half2 h01, h23;
        h01.x = __float2half(v.x); h01.y = __float2half(v.y);
        h23.x = __float2half(v.z); h23.y = __float2half(v.w);
        *reinterpret_cast<__half2*>(&wg_lds[j * 4])     = h01;
        *reinterpret_cast<__half2*>(&wg_lds[j * 4 + 2]) = h23;
    }
    if (threadIdx.x == 0)                     // tail: 40401 = 4*10100 + 1
        wg_lds[GRIDSZ - 1] = __float2half(wg[GRIDSZ - 1]);
    __syncthreads();

    float acc = 0.0f;
    const int stride = gridDim.x * blockDim.x;
    #pragma unroll 4
    for (int i = blockIdx.x * blockDim.x + threadIdx.x; i < n4; i += stride) {
        const float4 p = pred4[i];
        const float4 l = lab4[i];

        // row 0: (lat, lon) = (p.x, p.y)
        {
            const float e = fabsf(p.x - l.x) + fabsf(p.y - l.y);
            int xi = min(max((int)(p.x * 200.0f), 0), GRIDN - 1);
            int yi = min(max((int)(p.y * 200.0f), 0), GRIDN - 1);
            const float w = __half2float(wg_lds[xi * GRIDN + yi]);
            acc += e * fmaf(-ALPHA, w, 1.0f + ALPHA);
        }
        // row 1: (lat, lon) = (p.z, p.w)
        {
            const float e = fabsf(p.z - l.z) + fabsf(p.w - l.w);
            int xi = min(max((int)(p.z * 200.0f), 0), GRIDN - 1);
            int yi = min(max((int)(p.w * 200.0f), 0), GRIDN - 1);
            const float w = __half2float(wg_lds[xi * GRIDN + yi]);
            acc += e * fmaf(-ALPHA, w, 1.0f + ALPHA);
        }
    }

    // 64-lane wave reduction
    #pragma unroll
    for (int off = 32; off > 0; off >>= 1)
        acc += __shfl_down(acc, off, 64);

    __shared__ float red[16];
    const int lane = threadIdx.x & 63;
    const int wid  = threadIdx.x >> 6;
    if (lane == 0) red[wid] = acc;
    __syncthreads();
    if (threadIdx.x == 0) {
        float s = 0.0f;
        #pragma unroll
        for (int k = 0; k < 16; ++k) s += red[k];
        atomicAdd(out, s * scale);
    }
}

extern "C" void kernel_launch(void* const* d_in, const int* in_sizes, int n_in,
                              void* d_out, int out_size, void* d_ws, size_t ws_size,
                              hipStream_t stream) {
    const float4* pred = (const float4*)d_in[0];
    const float4* lab  = (const float4*)d_in[1];
    const float*  wg   = (const float*)d_in[2];
    float*        out  = (float*)d_out;

    const long long total = (long long)in_sizes[0];   // B*2 floats
    const int   n4    = (int)(total / 4);             // float4 count per array
    const float scale = 1.0f / (float)total;

    // d_out is re-poisoned to 0xAA before every timed launch -> zero it here.
    hipMemsetAsync(d_out, 0, sizeof(float), stream);

    const int block = 1024;   // 16 waves/block; 80.8 KB LDS -> 2 blocks/CU
    const int grid  = 512;    // 2 per CU; 8 main-loop iters/thread
    wmse_reduce<<<grid, block, 0, stream>>>(pred, lab, wg, out, n4, scale);
}

// Round 7
// 143.050 us; speedup vs baseline: 1.0749x; 1.0749x over previous
//
#include <hip/hip_runtime.h>
#include <hip/hip_fp16.h>

// WeightedMSELoss: mean over [B,2] of |pred-label| * (1 + a - a*w[cell(pred)])
// R5/R6: time pinned at 51 us regardless of occupancy/VALU/table-dtype;
// stream delivers 2.63 TB/s whether from HBM or L3 => hypothesis: L2-fill
// BW ceiling (~128 B/cyc/XCD * 8 = 2.46 TB/s). Test nontemporal loads on
// the streams; two-phase reduction into d_ws (no memset, no atomics).
// R6 fix: __builtin_nontemporal_load needs a native vector type, not
// HIP_vector_type -> use ext_vector_type(4) float.

typedef float f32x4 __attribute__((ext_vector_type(4)));

constexpr int   GRIDN  = 201;
constexpr int   GRIDSZ = GRIDN * GRIDN;   // 40401
constexpr float ALPHA  = 0.1f;
constexpr int   NBLK   = 512;

__global__ __launch_bounds__(1024, 8) void wmse_partial(
    const f32x4* __restrict__ pred4,
    const f32x4* __restrict__ lab4,
    const float* __restrict__ wg,
    float*       __restrict__ partials,
    int n4)
{
    __shared__ __half wg_lds[GRIDSZ];         // 80,802 B -> 2 blocks/CU

    // Stage + compress weight grid: vectorized f32x4 -> f16x4 (hits XCD L2).
    for (int j = threadIdx.x; j < GRIDSZ / 4; j += 1024) {
        const f32x4 v = ((const f32x4*)wg)[j];
        __half2 h01, h23;
        h01.x = __float2half(v.x); h01.y = __float2half(v.y);
        h23.x = __float2half(v.z); h23.y = __float2half(v.w);
        *reinterpret_cast<__half2*>(&wg_lds[j * 4])     = h01;
        *reinterpret_cast<__half2*>(&wg_lds[j * 4 + 2]) = h23;
    }
    if (threadIdx.x == 0)                     // tail: 40401 = 4*10100 + 1
        wg_lds[GRIDSZ - 1] = __float2half(wg[GRIDSZ - 1]);
    __syncthreads();

    float acc = 0.0f;
    const int stride = gridDim.x * blockDim.x;
    #pragma unroll 4
    for (int i = blockIdx.x * blockDim.x + threadIdx.x; i < n4; i += stride) {
        const f32x4 p = __builtin_nontemporal_load(&pred4[i]);
        const f32x4 l = __builtin_nontemporal_load(&lab4[i]);

        // row 0: (lat, lon) = (p.x, p.y)
        {
            const float e = fabsf(p.x - l.x) + fabsf(p.y - l.y);
            int xi = min(max((int)(p.x * 200.0f), 0), GRIDN - 1);
            int yi = min(max((int)(p.y * 200.0f), 0), GRIDN - 1);
            const float w = __half2float(wg_lds[xi * GRIDN + yi]);
            acc += e * fmaf(-ALPHA, w, 1.0f + ALPHA);
        }
        // row 1: (lat, lon) = (p.z, p.w)
        {
            const float e = fabsf(p.z - l.z) + fabsf(p.w - l.w);
            int xi = min(max((int)(p.z * 200.0f), 0), GRIDN - 1);
            int yi = min(max((int)(p.w * 200.0f), 0), GRIDN - 1);
            const float w = __half2float(wg_lds[xi * GRIDN + yi]);
            acc += e * fmaf(-ALPHA, w, 1.0f + ALPHA);
        }
    }

    // 64-lane wave reduction
    #pragma unroll
    for (int off = 32; off > 0; off >>= 1)
        acc += __shfl_down(acc, off, 64);

    __shared__ float red[16];
    const int lane = threadIdx.x & 63;
    const int wid  = threadIdx.x >> 6;
    if (lane == 0) red[wid] = acc;
    __syncthreads();
    if (threadIdx.x == 0) {
        float s = 0.0f;
        #pragma unroll
        for (int k = 0; k < 16; ++k) s += red[k];
        partials[blockIdx.x] = s;              // plain store; all NBLK written
    }
}

__global__ __launch_bounds__(512) void wmse_final(
    const float* __restrict__ partials, float* __restrict__ out, float scale)
{
    float v = partials[threadIdx.x];           // exactly NBLK=512 threads
    #pragma unroll
    for (int off = 32; off > 0; off >>= 1)
        v += __shfl_down(v, off, 64);
    __shared__ float red[8];
    const int lane = threadIdx.x & 63;
    const int wid  = threadIdx.x >> 6;
    if (lane == 0) red[wid] = v;
    __syncthreads();
    if (threadIdx.x == 0) {
        float s = 0.0f;
        #pragma unroll
        for (int k = 0; k < 8; ++k) s += red[k];
        out[0] = s * scale;
    }
}

extern "C" void kernel_launch(void* const* d_in, const int* in_sizes, int n_in,
                              void* d_out, int out_size, void* d_ws, size_t ws_size,
                              hipStream_t stream) {
    const f32x4* pred = (const f32x4*)d_in[0];
    const f32x4* lab  = (const f32x4*)d_in[1];
    const float* wg   = (const float*)d_in[2];
    float*       out  = (float*)d_out;
    float*       part = (float*)d_ws;         // NBLK floats of scratch

    const long long total = (long long)in_sizes[0];   // B*2 floats
    const int   n4    = (int)(total / 4);             // float4 count per array
    const float scale = 1.0f / (float)total;

    wmse_partial<<<NBLK, 1024, 0, stream>>>(pred, lab, wg, part, n4);
    wmse_final<<<1, 512, 0, stream>>>(part, out, scale);
}